// Round 14
// baseline (274.294 us; speedup 1.0000x reference)
//
#include <hip/hip_runtime.h>

// ---- problem constants ----
constexpr int B_    = 64;
constexpr int NPG_  = 512;
constexpr int D_    = 128;
constexpr int K_    = 5;
constexpr int NHID_ = 50;
constexpr int CB_   = 512;
constexpr int N_    = B_ * NPG_;   // 32768
constexpr int E_    = N_ * 16;     // 524288
constexpr float BN_SCALE_ = 0.99999500003749969f;  // 1/sqrt(1+1e-5)
constexpr float EPS_ = 1e-6f;

typedef __attribute__((ext_vector_type(8))) short bf16x8_t;
typedef __attribute__((ext_vector_type(4))) float f32x4_t;

__device__ __forceinline__ unsigned short f2bf(float x) {
    unsigned int u = __float_as_uint(x);
    unsigned int r = (u + 0x7FFFu + ((u >> 16) & 1u)) >> 16;   // RNE
    return (unsigned short)r;
}
__device__ __forceinline__ float bf2f(unsigned short b) {
    return __uint_as_float(((unsigned int)b) << 16);
}

// 2-term split product-sum: (a0+a1)(b0+b1) ~= a1*b0 + a0*b1 + a0*b0 (error ~2^-16)
__device__ __forceinline__ f32x4_t mfma3(bf16x8_t a0, bf16x8_t a1,
                                         bf16x8_t b0, bf16x8_t b1, f32x4_t acc) {
    acc = __builtin_amdgcn_mfma_f32_16x16x32_bf16(a1, b0, acc, 0, 0, 0);
    acc = __builtin_amdgcn_mfma_f32_16x16x32_bf16(a0, b1, acc, 0, 0, 0);
    acc = __builtin_amdgcn_mfma_f32_16x16x32_bf16(a0, b0, acc, 0, 0, 0);
    return acc;
}

// =================== fused prep (weight split) + per-graph CSR build ===================
// blocks 0..63: CSR. blocks 64..447: GIN weight split. blocks 448..463: part_W1 split.
__global__ __launch_bounds__(512) void k_prepcsr(
    const int* __restrict__ dst, int* __restrict__ rowptr, int* __restrict__ col,
    const float* __restrict__ gw1, const float* __restrict__ gw2,
    unsigned short* __restrict__ w1h, unsigned short* __restrict__ w1l,
    unsigned short* __restrict__ w2h, unsigned short* __restrict__ w2l,
    const float* __restrict__ pw1src,
    unsigned short* __restrict__ pw1h, unsigned short* __restrict__ pw1l) {
    __shared__ int cnt[512];
    __shared__ int sc[512];
    __shared__ short dstS[8192];
    int b = blockIdx.x, t = threadIdx.x;
    if (b >= 448) {
        // part_W1 [128][50] -> padded [128][64], B-fragment order
        int e2 = (b - 448) * 512 + t;   // 0..8191
        int k = e2 >> 6, n = e2 & 63;
        float v = (n < NHID_) ? pw1src[k * NHID_ + n] : 0.f;
        unsigned short h0 = f2bf(v);
        int o = ((((n >> 4) * 4 + (k >> 5)) * 64 + ((k >> 3) & 3) * 16 + (n & 15)) << 3) + (k & 7);
        pw1h[o] = h0; pw1l[o] = f2bf(v - bf2f(h0));
        return;
    }
    if (b >= 64) {
        int e = (b - 64) * 512 + t;   // 0..196607
        int layer = e >> 16, rem = e & 65535;
        if (rem < 32768) {
            int k = rem >> 8, n = rem & 255;        // W1[k][n], K=128, N=256
            float v = gw1[layer * 32768 + rem];
            unsigned short h0 = f2bf(v);
            int o = layer * 32768 +
                    ((((n >> 4) * 4 + (k >> 5)) * 64 + ((k >> 3) & 3) * 16 + (n & 15)) << 3) + (k & 7);
            w1h[o] = h0; w1l[o] = f2bf(v - bf2f(h0));
        } else {
            int rr = rem - 32768;
            int c = rr >> 7, n = rr & 127;          // W2[c][n], K=256, N=128
            float v = gw2[layer * 32768 + rr];
            unsigned short h0 = f2bf(v);
            int o = layer * 32768 +
                    ((((n >> 4) * 8 + (c >> 5)) * 64 + ((c >> 3) & 3) * 16 + (n & 15)) << 3) + (c & 7);
            w2h[o] = h0; w2l[o] = f2bf(v - bf2f(h0));
        }
        return;
    }
    int g = b;
    int base = g * 8192;
    cnt[t] = 0;
    __syncthreads();
    for (int i = t; i < 8192; i += 512) {
        int d = dst[base + i] & 511;
        dstS[i] = (short)d;
        atomicAdd(&cnt[d], 1);
    }
    __syncthreads();
    int c0 = cnt[t];
    sc[t] = c0;
    __syncthreads();
    for (int off = 1; off < 512; off <<= 1) {
        int v = sc[t];
        int add = (t >= off) ? sc[t - off] : 0;
        __syncthreads();
        sc[t] = v + add;
        __syncthreads();
    }
    int excl = sc[t] - c0;
    rowptr[g * 512 + t] = base + excl;
    cnt[t] = excl;
    if (g == 0 && t == 0) rowptr[N_] = E_;
    __syncthreads();
    for (int i = t; i < 8192; i += 512) {
        int d = dstS[i];
        int p = atomicAdd(&cnt[d], 1);
        col[base + p] = g * 512 + (i >> 4);
    }
}

// =================== fused GIN layer: 16-row tiles, 256 threads, 2048 blocks ===================
// ~20 KB LDS -> 7-8 blocks/CU for cross-block phase diversity.
// L0: gather emb via L1 (10.75 KB table, L1-resident) with xS index staging.
// LAST: fused partitioner via MFMA epilogue.
constexpr int LDH = 264;
constexpr int COLCAP = 640;
template<int L0, int LAST>
__global__ __launch_bounds__(256, 8) void k_gin(
    const float* __restrict__ hIn, const int* __restrict__ rowptr,
    const int* __restrict__ col,
    const int* __restrict__ xIdx, const float* __restrict__ emb,
    const unsigned short* __restrict__ w1h, const unsigned short* __restrict__ w1l,
    const unsigned short* __restrict__ w2h, const unsigned short* __restrict__ w2l,
    const float* __restrict__ b1, const float* __restrict__ b2,
    const float* __restrict__ gamma, const float* __restrict__ beta,
    int relu_out, float* __restrict__ hOut,
    const unsigned short* __restrict__ pw1h, const unsigned short* __restrict__ pw1l,
    const float* __restrict__ pb1,
    const float* __restrict__ pW2, const float* __restrict__ pb2,
    float* __restrict__ pacc, float* __restrict__ pss, float* __restrict__ prs) {
    __shared__ int colS[COLCAP];
    __shared__ __attribute__((aligned(16))) unsigned short bufH[16 * LDH];
    __shared__ __attribute__((aligned(16))) unsigned short bufL[16 * LDH];
    __shared__ int xS[L0 ? 512 : 1];
    __shared__ float ltS[LAST ? 16 * 5 : 1];
    int i = blockIdx.x;
    int xcd = i & 7;
    int slot = i >> 3;              // 0..255
    int g = (slot >> 5) * 8 + xcd;  // 0..63
    int tile = slot & 31;           // 0..31
    int rowBase = g * 512 + tile * 16;
    int t = threadIdx.x;            // 0..255
    int w = t >> 6, l = t & 63;     // 4 waves
    int l15 = l & 15, quad = l >> 4;
    int half = l >> 5, lane4 = l & 31;

    int ebase = rowptr[rowBase];
    int ecnt  = rowptr[rowBase + 16] - ebase;
    bool inLds = (ecnt <= COLCAP);
    if (inLds)
        for (int j = t; j < ecnt; j += 256) colS[j] = col[ebase + j];
    if constexpr (L0)
        for (int j = t; j < 512; j += 256) xS[j] = xIdx[(rowBase & ~511) + j];
    __syncthreads();

    const f32x4_t* h4 = (const f32x4_t*)hIn;
    const f32x4_t* e4 = (const f32x4_t*)emb;
    #pragma unroll
    for (int jj = 0; jj < 2; jj++) {
        int row = w * 4 + half * 2 + jj;   // 0..15
        int node = rowBase + row;
        int beg = rowptr[node], end = rowptr[node + 1];
        f32x4_t a;
        if constexpr (L0)
            a = e4[xS[node & 511] * 32 + lane4];
        else
            a = h4[node * 32 + lane4];
        int e = beg;
        for (; e + 8 <= end; e += 8) {
            int c[8];
            #pragma unroll
            for (int u = 0; u < 8; u++)
                c[u] = inLds ? colS[e - ebase + u] : col[e + u];
            f32x4_t p[8];
            #pragma unroll
            for (int u = 0; u < 8; u++) {
                if constexpr (L0)
                    p[u] = e4[xS[c[u] & 511] * 32 + lane4];
                else
                    p[u] = h4[c[u] * 32 + lane4];
            }
            f32x4_t s01 = p[0] + p[1], s23 = p[2] + p[3];
            f32x4_t s45 = p[4] + p[5], s67 = p[6] + p[7];
            a += (s01 + s23) + (s45 + s67);
        }
        for (; e < end; e++) {
            int c = inLds ? colS[e - ebase] : col[e];
            f32x4_t p;
            if constexpr (L0)
                p = e4[xS[c & 511] * 32 + lane4];
            else
                p = h4[c * 32 + lane4];
            a += p;
        }
        unsigned short h0 = f2bf(a[0]), h1 = f2bf(a[1]), h2s = f2bf(a[2]), h3 = f2bf(a[3]);
        uint2 hv, lv;
        hv.x = (unsigned)h0 | ((unsigned)h1 << 16);
        hv.y = (unsigned)h2s | ((unsigned)h3 << 16);
        lv.x = (unsigned)f2bf(a[0] - bf2f(h0)) | ((unsigned)f2bf(a[1] - bf2f(h1)) << 16);
        lv.y = (unsigned)f2bf(a[2] - bf2f(h2s)) | ((unsigned)f2bf(a[3] - bf2f(h3)) << 16);
        *(uint2*)&bufH[row * LDH + lane4 * 4] = hv;
        *(uint2*)&bufL[row * LDH + lane4 * 4] = lv;
    }
    __syncthreads();

    // ---- MLP1: wave w owns 4 column-tiles (N=256), M=16 ----
    f32x4_t acc1[4];
    #pragma unroll
    for (int nt = 0; nt < 4; nt++) {
        float bb = b1[(w * 4 + nt) * 16 + l15];
        acc1[nt] = (f32x4_t){bb, bb, bb, bb};
    }
    #pragma unroll
    for (int kk = 0; kk < 4; kk++) {
        int addr = l15 * LDH + kk * 32 + quad * 8;
        bf16x8_t ah = *(const bf16x8_t*)&bufH[addr];
        bf16x8_t al = *(const bf16x8_t*)&bufL[addr];
        #pragma unroll
        for (int nt = 0; nt < 4; nt++) {
            int n16 = w * 4 + nt;
            int ga = (((n16 * 4 + kk) * 64 + l) << 3);
            bf16x8_t bh = *(const bf16x8_t*)&w1h[ga];
            bf16x8_t bl = *(const bf16x8_t*)&w1l[ga];
            acc1[nt] = mfma3(ah, al, bh, bl, acc1[nt]);
        }
    }
    __syncthreads();
    #pragma unroll
    for (int nt = 0; nt < 4; nt++) {
        int colL = (w * 4 + nt) * 16 + l15;
        #pragma unroll
        for (int r = 0; r < 4; r++) {
            int row = quad * 4 + r;
            float v = fmaxf(acc1[nt][r], 0.f);
            unsigned short h0 = f2bf(v);
            bufH[row * LDH + colL] = h0;
            bufL[row * LDH + colL] = f2bf(v - bf2f(h0));
        }
    }
    __syncthreads();

    // ---- MLP2: wave w owns 2 column-tiles (N=128), K=256 ----
    f32x4_t acc2[2];
    #pragma unroll
    for (int nt2 = 0; nt2 < 2; nt2++) {
        float bb = b2[(w * 2 + nt2) * 16 + l15];
        acc2[nt2] = (f32x4_t){bb, bb, bb, bb};
    }
    #pragma unroll
    for (int kkG = 0; kkG < 8; kkG++) {
        int addr = l15 * LDH + kkG * 32 + quad * 8;
        bf16x8_t ah = *(const bf16x8_t*)&bufH[addr];
        bf16x8_t al = *(const bf16x8_t*)&bufL[addr];
        #pragma unroll
        for (int nt2 = 0; nt2 < 2; nt2++) {
            int ga = ((((w * 2 + nt2) * 8 + kkG) * 64 + l) << 3);
            bf16x8_t bh = *(const bf16x8_t*)&w2h[ga];
            bf16x8_t bl = *(const bf16x8_t*)&w2l[ga];
            acc2[nt2] = mfma3(ah, al, bh, bl, acc2[nt2]);
        }
    }
    // ---- BN (+ReLU) ----
    if constexpr (!LAST) {
        #pragma unroll
        for (int nt2 = 0; nt2 < 2; nt2++) {
            int colC = (w * 2 + nt2) * 16 + l15;
            float gm = BN_SCALE_ * gamma[colC];
            float be = beta[colC];
            #pragma unroll
            for (int r = 0; r < 4; r++) {
                int row = quad * 4 + r;
                float v = fmaf(acc2[nt2][r], gm, be);
                if (relu_out) v = fmaxf(v, 0.f);
                hOut[(size_t)(rowBase + row) * 128 + colC] = v;
            }
        }
    } else {
        // ============ fused partitioner (MFMA MLP1) + cf1 partials per 16-node chunk ============
        __syncthreads();   // main-path bufH/bufL reads done; safe to overwrite
        #pragma unroll
        for (int nt2 = 0; nt2 < 2; nt2++) {
            int colC = (w * 2 + nt2) * 16 + l15;
            float gm = BN_SCALE_ * gamma[colC];
            float be = beta[colC];
            #pragma unroll
            for (int r = 0; r < 4; r++) {
                int row = quad * 4 + r;
                float v = fmaf(acc2[nt2][r], gm, be);   // no relu (last layer)
                unsigned short h0 = f2bf(v);
                bufH[row * LDH + colC] = h0;
                bufL[row * LDH + colC] = f2bf(v - bf2f(h0));
            }
        }
        __syncthreads();
        // part-MLP1 via MFMA: wave w owns output tile w (N=64 padded)
        {
            int ocol = w * 16 + l15;
            float bb = (ocol < NHID_) ? pb1[ocol] : 0.f;
            f32x4_t acch = (f32x4_t){bb, bb, bb, bb};
            #pragma unroll
            for (int kk = 0; kk < 4; kk++) {
                int addr = l15 * LDH + kk * 32 + quad * 8;
                bf16x8_t ah = *(const bf16x8_t*)&bufH[addr];
                bf16x8_t al = *(const bf16x8_t*)&bufL[addr];
                int ga = (((w * 4 + kk) * 64 + l) << 3);
                bf16x8_t bh = *(const bf16x8_t*)&pw1h[ga];
                bf16x8_t bl = *(const bf16x8_t*)&pw1l[ga];
                acch = mfma3(ah, al, bh, bl, acch);
            }
            float* htF = (float*)bufH;   // cols 128.. of bufH (float view: row*132 + 64 + col)
            #pragma unroll
            for (int r = 0; r < 4; r++) {
                int row = quad * 4 + r;
                htF[row * 132 + 64 + ocol] = fmaxf(acch[r], 0.f);
            }
        }
        __syncthreads();
        // MLP2 logits: lt = ht @ pW2 + pb2, pW2 [50][5]
        {
            float* htF = (float*)bufH;
            if (t < 80) {
                int row = t / 5, kk5 = t % 5;
                float a = pb2[kk5];
                for (int c = 0; c < NHID_; c++)
                    a = fmaf(htF[row * 132 + 64 + c], pW2[c * K_ + kk5], a);
                ltS[row * 5 + kk5] = a;
            }
        }
        __syncthreads();
        // softmax per row
        if (t < 16) {
            float l0 = ltS[t*5], l1 = ltS[t*5+1], l2 = ltS[t*5+2],
                  l3 = ltS[t*5+3], l4 = ltS[t*5+4];
            float m = fmaxf(fmaxf(fmaxf(l0, l1), fmaxf(l2, l3)), l4);
            float e0 = expf(l0 - m), e1 = expf(l1 - m), e2 = expf(l2 - m),
                  e3 = expf(l3 - m), e4 = expf(l4 - m);
            float inv = 1.0f / (e0 + e1 + e2 + e3 + e4);
            ltS[t*5]   = e0*inv; ltS[t*5+1] = e1*inv; ltS[t*5+2] = e2*inv;
            ltS[t*5+3] = e3*inv; ltS[t*5+4] = e4*inv;
        }
        __syncthreads();
        // partials: pacc[c][k][d], prs[c][d], pss[c][k]; z reconstructed = hi+lo
        int cIdx = g * 32 + tile;
        for (int j = t; j < 640; j += 256) {
            int k = j >> 7, d = j & 127;
            float a = 0;
            #pragma unroll 8
            for (int r = 0; r < 16; r++) {
                float zv = bf2f(bufH[r * LDH + d]) + bf2f(bufL[r * LDH + d]);
                a = fmaf(ltS[r * 5 + k], zv, a);
            }
            pacc[((size_t)cIdx * 5 + k) * 128 + d] = a;
        }
        if (t < 128) {
            float a = 0;
            #pragma unroll 8
            for (int r = 0; r < 16; r++)
                a += bf2f(bufH[r * LDH + t]) + bf2f(bufL[r * LDH + t]);
            prs[cIdx * 128 + t] = a;
        } else if (t < 133) {
            int k = t - 128;
            float a = 0;
            #pragma unroll 8
            for (int r = 0; r < 16; r++) a += ltS[r * 5 + k];
            pss[cIdx * 5 + k] = a;
        }
    }
}

// =================== fused tail (P1 over 32 chunks of 16; multi-acc ILP) ===================
__global__ __launch_bounds__(1024) void k_tail(
    const float* __restrict__ pacc, const float* __restrict__ pss,
    const float* __restrict__ prs, const float* __restrict__ cbk,
    const float* __restrict__ Wq, const float* __restrict__ Wk,
    const float* __restrict__ Wv, const float* __restrict__ Wo,
    const float* __restrict__ gW1, const float* __restrict__ gb1,
    const float* __restrict__ gW2, const float* __restrict__ gb2,
    const float* __restrict__ cW1, const float* __restrict__ cb1,
    const float* __restrict__ cW2, const float* __restrict__ cb2,
    const float* __restrict__ cW3, const float* __restrict__ cb3,
    float* __restrict__ out) {
    __shared__ float cfS[5 * 128];
    __shared__ float zqS[5 * 128];
    __shared__ float catS[256];
    __shared__ float qS[128];
    __shared__ float kS[5 * 128];
    __shared__ float vS[5 * 128];
    __shared__ float awS[20];
    __shared__ float att1S[128];
    __shared__ float attP[4][128];
    __shared__ float g1P[8][64];
    __shared__ float g1S[64];
    __shared__ float g2P[4][128];
    __shared__ float fusedS[128];
    __shared__ float z1P[2][512];
    __shared__ float z1S[512];
    __shared__ float z2P[4][256];
    __shared__ float bd5[5][512];
    __shared__ int   bi5[5][512];
    __shared__ int   idxS[5];
    __shared__ float red[8];

    int g = blockIdx.x, t = threadIdx.x;

    // ---- Phase 1: reduce cf partials + residue (32 chunks of 16 nodes) ----
    if (t < 768) {
        int c = t >> 7, d = t & 127;
        if (c == 5) {
            float rs = 0;
            #pragma unroll
            for (int ch = 0; ch < 32; ch++) rs += prs[(g * 32 + ch) * 128 + d];
            catS[d] = rs * (1.0f / 512.0f);
        } else {
            float acc = 0, ss = 0;
            #pragma unroll
            for (int ch = 0; ch < 32; ch++) {
                int blk = g * 32 + ch;
                acc += pacc[((size_t)blk * 5 + c) * 128 + d];
                ss  += pss[blk * 5 + c];
            }
            cfS[c * 128 + d] = acc / (ss + EPS_);
        }
    }
    __syncthreads();

    // ---- Phase 2: VQ argmin ----
    if (t < 512) {
        const float4* cj = (const float4*)(cbk + (size_t)t * 128);
        float d2[5] = {0, 0, 0, 0, 0};
        #pragma unroll 8
        for (int q4 = 0; q4 < 32; q4++) {
            float4 c4 = cj[q4];
            #pragma unroll
            for (int k = 0; k < 5; k++) {
                float4 f4 = ((const float4*)(cfS + k * 128))[q4];
                float dx = f4.x - c4.x, dy = f4.y - c4.y;
                float dz = f4.z - c4.z, dw = f4.w - c4.w;
                d2[k] = fmaf(dx, dx, d2[k]); d2[k] = fmaf(dy, dy, d2[k]);
                d2[k] = fmaf(dz, dz, d2[k]); d2[k] = fmaf(dw, dw, d2[k]);
            }
        }
        #pragma unroll
        for (int k = 0; k < 5; k++) { bd5[k][t] = d2[k]; bi5[k][t] = t; }
    }
    __syncthreads();
    for (int s = 256; s > 0; s >>= 1) {
        if (t < s) {
            #pragma unroll
            for (int k = 0; k < 5; k++) {
                float bo = bd5[k][t + s]; int io = bi5[k][t + s];
                if (bo < bd5[k][t] || (bo == bd5[k][t] && io < bi5[k][t])) {
                    bd5[k][t] = bo; bi5[k][t] = io;
                }
            }
        }
        __syncthreads();
    }
    if (t < 5) idxS[t] = bi5[t][0];
    __syncthreads();
    if (t < 640) zqS[t] = cbk[(size_t)idxS[t >> 7] * 128 + (t & 127)];
    __syncthreads();

    // ---- Phase 3: q/k/v projections (4 independent accumulator chains) ----
    for (int o = t; o < 1408; o += 1024) {
        const float* Arow; const float* W; int dcol;
        if (o < 128)      { Arow = catS;                     W = Wq; dcol = o; }
        else if (o < 768) { Arow = &zqS[((o - 128) >> 7) * 128]; W = Wk; dcol = (o - 128) & 127; }
        else              { Arow = &zqS[((o - 768) >> 7) * 128]; W = Wv; dcol = (o - 768) & 127; }
        float a0 = 0, a1 = 0, a2 = 0, a3 = 0;
        for (int kk = 0; kk < 128; kk += 4) {
            a0 = fmaf(Arow[kk],     W[kk * 128 + dcol],       a0);
            a1 = fmaf(Arow[kk + 1], W[(kk + 1) * 128 + dcol], a1);
            a2 = fmaf(Arow[kk + 2], W[(kk + 2) * 128 + dcol], a2);
            a3 = fmaf(Arow[kk + 3], W[(kk + 3) * 128 + dcol], a3);
        }
        float acc = (a0 + a1) + (a2 + a3);
        if (o < 128)      qS[o] = acc;
        else if (o < 768) kS[o - 128] = acc;
        else              vS[o - 768] = acc;
    }
    __syncthreads();

    // ---- Phase 4: attention ----
    if (t < 20) {
        int hh = t / 5, j = t % 5;
        float s = 0;
        #pragma unroll
        for (int d2 = 0; d2 < 32; d2++)
            s = fmaf(qS[hh * 32 + d2], kS[j * 128 + hh * 32 + d2], s);
        awS[t] = s * 0.17677669529663687f;
    }
    __syncthreads();
    if (t < 4) {
        float m = -1e30f;
        for (int j = 0; j < 5; j++) m = fmaxf(m, awS[t * 5 + j]);
        float e[5], sum = 0;
        for (int j = 0; j < 5; j++) { e[j] = expf(awS[t * 5 + j] - m); sum += e[j]; }
        for (int j = 0; j < 5; j++) awS[t * 5 + j] = e[j] / sum;
    }
    __syncthreads();
    if (t < 128) {
        int hh = t >> 5;
        float a = 0;
        #pragma unroll
        for (int j = 0; j < 5; j++) a = fmaf(awS[hh * 5 + j], vS[j * 128 + t], a);
        att1S[t] = a;
    }
    __syncthreads();
    if (t < 512) {
        int o = t & 127, kq = t >> 7;
        float a0 = 0, a1 = 0;
        #pragma unroll 8
        for (int i = 0; i < 32; i += 2) {
            int kk = kq * 32 + i;
            a0 = fmaf(att1S[kk],     Wo[kk * 128 + o],       a0);
            a1 = fmaf(att1S[kk + 1], Wo[(kk + 1) * 128 + o], a1);
        }
        attP[kq][o] = a0 + a1;
    }
    __syncthreads();
    if (t < 128) catS[128 + t] = attP[0][t] + attP[1][t] + attP[2][t] + attP[3][t];
    __syncthreads();

    // ---- Phase 5: gate ----
    if (t < 512) {
        int o = t & 63, kq = t >> 6;
        float a0 = 0, a1 = 0;
        #pragma unroll 8
        for (int i = 0; i < 32; i += 2) {
            int kk = kq * 32 + i;
            a0 = fmaf(catS[kk],     gW1[kk * 64 + o],       a0);
            a1 = fmaf(catS[kk + 1], gW1[(kk + 1) * 64 + o], a1);
        }
        g1P[kq][o] = a0 + a1;
    }
    __syncthreads();
    if (t < 64) {
        float a = gb1[t];
        #pragma unroll
        for (int q = 0; q < 8; q++) a += g1P[q][t];
        g1S[t] = fmaxf(a, 0.f);
    }
    __syncthreads();
    if (t < 512) {
        int o = t & 127, kq = t >> 7;
        float a0 = 0, a1 = 0;
        #pragma unroll 8
        for (int i = 0; i < 16; i += 2) {
            int kk = kq * 16 + i;
            a0 = fmaf(g1S[kk],     gW2[kk * 128 + o],       a0);
            a1 = fmaf(g1S[kk + 1], gW2[(kk + 1) * 128 + o], a1);
        }
        g2P[kq][o] = a0 + a1;
    }
    __syncthreads();
    if (t < 128) {
        float a = gb2[t] + g2P[0][t] + g2P[1][t] + g2P[2][t] + g2P[3][t];
        float gv = 1.f / (1.f + expf(-a));
        fusedS[t] = gv * catS[t] + (1.f - gv) * catS[128 + t];
    }
    __syncthreads();

    // ---- Phase 6: classifier ----
    {
        int o = t & 511, kq = t >> 9;
        float a0 = 0, a1 = 0, a2 = 0, a3 = 0;
        #pragma unroll 4
        for (int i = 0; i < 64; i += 4) {
            int kk = kq * 64 + i;
            a0 = fmaf(fusedS[kk],     cW1[kk * 512 + o],       a0);
            a1 = fmaf(fusedS[kk + 1], cW1[(kk + 1) * 512 + o], a1);
            a2 = fmaf(fusedS[kk + 2], cW1[(kk + 2) * 512 + o], a2);
            a3 = fmaf(fusedS[kk + 3], cW1[(kk + 3) * 512 + o], a3);
        }
        z1P[kq][o] = (a0 + a1) + (a2 + a3);
    }
    __syncthreads();
    if (t < 512) z1S[t] = fmaxf(z1P[0][t] + z1P[1][t] + cb1[t], 0.f);
    __syncthreads();
    {
        int o = t & 255, kq = t >> 8;
        float a0 = 0, a1 = 0, a2 = 0, a3 = 0;
        #pragma unroll 4
        for (int i = 0; i < 128; i += 4) {
            int kk = kq * 128 + i;
            a0 = fmaf(z1S[kk],     cW2[kk * 256 + o],       a0);
            a1 = fmaf(z1S[kk + 1], cW2[(kk + 1) * 256 + o], a1);
            a2 = fmaf(z1S[kk + 2], cW2[(kk + 2) * 256 + o], a2);
            a3 = fmaf(z1S[kk + 3], cW2[(kk + 3) * 256 + o], a3);
        }
        z2P[kq][o] = (a0 + a1) + (a2 + a3);
    }
    __syncthreads();
    if (t < 256) {
        float zv = fmaxf(z2P[0][t] + z2P[1][t] + z2P[2][t] + z2P[3][t] + cb2[t], 0.f);
        float p0 = zv * cW3[t * 2];
        float p1 = zv * cW3[t * 2 + 1];
        #pragma unroll
        for (int off = 32; off > 0; off >>= 1) {
            p0 += __shfl_down(p0, off, 64);
            p1 += __shfl_down(p1, off, 64);
        }
        int wv = t >> 6;
        if ((t & 63) == 0) { red[wv * 2] = p0; red[wv * 2 + 1] = p1; }
    }
    __syncthreads();
    if (t < 2)
        out[g * 2 + t] = cb3[t] + red[t] + red[2 + t] + red[4 + t] + red[6 + t];
}

// =================== launch ===================
extern "C" void kernel_launch(void* const* d_in, const int* in_sizes, int n_in,
                              void* d_out, int out_size, void* d_ws, size_t ws_size,
                              hipStream_t stream) {
    const int*   x          = (const int*)d_in[0];
    const int*   edge_index = (const int*)d_in[1];
    const float* emb      = (const float*)d_in[3];
    const float* gin_W1   = (const float*)d_in[4];
    const float* gin_b1   = (const float*)d_in[5];
    const float* gin_W2   = (const float*)d_in[6];
    const float* gin_b2   = (const float*)d_in[7];
    const float* bn_gamma = (const float*)d_in[8];
    const float* bn_beta  = (const float*)d_in[9];
    const float* part_W1  = (const float*)d_in[10];
    const float* part_b1  = (const float*)d_in[11];
    const float* part_W2  = (const float*)d_in[12];
    const float* part_b2  = (const float*)d_in[13];
    const float* Wq       = (const float*)d_in[14];
    const float* Wk       = (const float*)d_in[15];
    const float* Wv       = (const float*)d_in[16];
    const float* Wo       = (const float*)d_in[17];
    const float* gate_W1  = (const float*)d_in[18];
    const float* gate_b1  = (const float*)d_in[19];
    const float* gate_W2  = (const float*)d_in[20];
    const float* gate_b2  = (const float*)d_in[21];
    const float* codebook = (const float*)d_in[22];
    const float* cls_W1   = (const float*)d_in[23];
    const float* cls_b1   = (const float*)d_in[24];
    const float* cls_W2   = (const float*)d_in[25];
    const float* cls_b2   = (const float*)d_in[26];
    const float* cls_W3   = (const float*)d_in[27];
    const float* cls_b3   = (const float*)d_in[28];

    const int* dstp = edge_index + E_;

    // ---- workspace carve ----
    char* w = (char*)d_ws;
    float* hA = (float*)w;  w += (size_t)N_ * D_ * 4;   // L1 out
    float* hB = (float*)w;  w += (size_t)N_ * D_ * 4;   // L0 out
    int* rowptr = (int*)w;  w += (size_t)(N_ + 4) * 4;
    int* col    = (int*)w;  w += (size_t)E_ * 4;
    unsigned short* w1h = (unsigned short*)w;  w += (size_t)3 * 32768 * 2;
    unsigned short* w1l = (unsigned short*)w;  w += (size_t)3 * 32768 * 2;
    unsigned short* w2h = (unsigned short*)w;  w += (size_t)3 * 32768 * 2;
    unsigned short* w2l = (unsigned short*)w;  w += (size_t)3 * 32768 * 2;
    unsigned short* pw1h = (unsigned short*)w;  w += (size_t)8192 * 2;
    unsigned short* pw1l = (unsigned short*)w;  w += (size_t)8192 * 2;
    float* pacc = (float*)w;  w += (size_t)2048 * 5 * 128 * 4;
    float* pss  = (float*)w;  w += (size_t)2048 * 5 * 4;
    float* prs  = (float*)w;  w += (size_t)2048 * 128 * 4;

    // ---- prep + CSR (64 csr + 384 gin-weight + 16 part-W1 blocks) ----
    k_prepcsr<<<464, 512, 0, stream>>>(dstp, rowptr, col,
                                       gin_W1, gin_W2, w1h, w1l, w2h, w2l,
                                       part_W1, pw1h, pw1l);

    // ---- GIN: L0 (emb via L1) -> hB; L1 hB -> hA; L2 hA -> fused partcf partials ----
    k_gin<1, 0><<<2048, 256, 0, stream>>>(
        hA, rowptr, col, x, emb,
        w1h, w1l, w2h, w2l,
        gin_b1, gin_b2, bn_gamma, bn_beta, 1, hB,
        nullptr, nullptr, nullptr, nullptr, nullptr, nullptr, nullptr, nullptr);
    k_gin<0, 0><<<2048, 256, 0, stream>>>(
        hB, rowptr, col, x, emb,
        w1h + 32768, w1l + 32768, w2h + 32768, w2l + 32768,
        gin_b1 + 256, gin_b2 + 128, bn_gamma + 128, bn_beta + 128, 1, hA,
        nullptr, nullptr, nullptr, nullptr, nullptr, nullptr, nullptr, nullptr);
    k_gin<0, 1><<<2048, 256, 0, stream>>>(
        hA, rowptr, col, x, emb,
        w1h + 65536, w1l + 65536, w2h + 65536, w2l + 65536,
        gin_b1 + 512, gin_b2 + 256, bn_gamma + 256, bn_beta + 256, 0, nullptr,
        pw1h, pw1l, part_b1, part_W2, part_b2, pacc, pss, prs);

    // ---- tail ----
    k_tail<<<B_, 1024, 0, stream>>>(pacc, pss, prs, codebook,
                                    Wq, Wk, Wv, Wo,
                                    gate_W1, gate_b1, gate_W2, gate_b2,
                                    cls_W1, cls_b1, cls_W2, cls_b2, cls_W3, cls_b3,
                                    (float*)d_out);
}

// Round 15
// 250.538 us; speedup vs baseline: 1.0948x; 1.0948x over previous
//
#include <hip/hip_runtime.h>

// ---- problem constants ----
constexpr int B_    = 64;
constexpr int NPG_  = 512;
constexpr int D_    = 128;
constexpr int K_    = 5;
constexpr int NHID_ = 50;
constexpr int CB_   = 512;
constexpr int N_    = B_ * NPG_;   // 32768
constexpr int E_    = N_ * 16;     // 524288
constexpr float BN_SCALE_ = 0.99999500003749969f;  // 1/sqrt(1+1e-5)
constexpr float EPS_ = 1e-6f;

typedef __attribute__((ext_vector_type(8))) short bf16x8_t;
typedef __attribute__((ext_vector_type(4))) float f32x4_t;

__device__ __forceinline__ unsigned short f2bf(float x) {
    unsigned int u = __float_as_uint(x);
    unsigned int r = (u + 0x7FFFu + ((u >> 16) & 1u)) >> 16;   // RNE
    return (unsigned short)r;
}
__device__ __forceinline__ float bf2f(unsigned short b) {
    return __uint_as_float(((unsigned int)b) << 16);
}

// 2-term split product-sum: (a0+a1)(b0+b1) ~= a1*b0 + a0*b1 + a0*b0 (error ~2^-16)
__device__ __forceinline__ f32x4_t mfma3(bf16x8_t a0, bf16x8_t a1,
                                         bf16x8_t b0, bf16x8_t b1, f32x4_t acc) {
    acc = __builtin_amdgcn_mfma_f32_16x16x32_bf16(a1, b0, acc, 0, 0, 0);
    acc = __builtin_amdgcn_mfma_f32_16x16x32_bf16(a0, b1, acc, 0, 0, 0);
    acc = __builtin_amdgcn_mfma_f32_16x16x32_bf16(a0, b0, acc, 0, 0, 0);
    return acc;
}

// =================== fused prep (weight split) + per-graph CSR build ===================
// blocks 0..63: CSR. blocks 64..447: GIN weight split. blocks 448..463: part_W1 split.
__global__ __launch_bounds__(512) void k_prepcsr(
    const int* __restrict__ dst, int* __restrict__ rowptr, int* __restrict__ col,
    const float* __restrict__ gw1, const float* __restrict__ gw2,
    unsigned short* __restrict__ w1h, unsigned short* __restrict__ w1l,
    unsigned short* __restrict__ w2h, unsigned short* __restrict__ w2l,
    const float* __restrict__ pw1src,
    unsigned short* __restrict__ pw1h, unsigned short* __restrict__ pw1l) {
    __shared__ int cnt[512];
    __shared__ int sc[512];
    __shared__ short dstS[8192];
    int b = blockIdx.x, t = threadIdx.x;
    if (b >= 448) {
        // part_W1 [128][50] -> padded [128][64], B-fragment order
        int e2 = (b - 448) * 512 + t;   // 0..8191
        int k = e2 >> 6, n = e2 & 63;
        float v = (n < NHID_) ? pw1src[k * NHID_ + n] : 0.f;
        unsigned short h0 = f2bf(v);
        int o = ((((n >> 4) * 4 + (k >> 5)) * 64 + ((k >> 3) & 3) * 16 + (n & 15)) << 3) + (k & 7);
        pw1h[o] = h0; pw1l[o] = f2bf(v - bf2f(h0));
        return;
    }
    if (b >= 64) {
        int e = (b - 64) * 512 + t;   // 0..196607
        int layer = e >> 16, rem = e & 65535;
        if (rem < 32768) {
            int k = rem >> 8, n = rem & 255;        // W1[k][n], K=128, N=256
            float v = gw1[layer * 32768 + rem];
            unsigned short h0 = f2bf(v);
            int o = layer * 32768 +
                    ((((n >> 4) * 4 + (k >> 5)) * 64 + ((k >> 3) & 3) * 16 + (n & 15)) << 3) + (k & 7);
            w1h[o] = h0; w1l[o] = f2bf(v - bf2f(h0));
        } else {
            int rr = rem - 32768;
            int c = rr >> 7, n = rr & 127;          // W2[c][n], K=256, N=128
            float v = gw2[layer * 32768 + rr];
            unsigned short h0 = f2bf(v);
            int o = layer * 32768 +
                    ((((n >> 4) * 8 + (c >> 5)) * 64 + ((c >> 3) & 3) * 16 + (n & 15)) << 3) + (c & 7);
            w2h[o] = h0; w2l[o] = f2bf(v - bf2f(h0));
        }
        return;
    }
    int g = b;
    int base = g * 8192;
    cnt[t] = 0;
    __syncthreads();
    for (int i = t; i < 8192; i += 512) {
        int d = dst[base + i] & 511;
        dstS[i] = (short)d;
        atomicAdd(&cnt[d], 1);
    }
    __syncthreads();
    int c0 = cnt[t];
    sc[t] = c0;
    __syncthreads();
    for (int off = 1; off < 512; off <<= 1) {
        int v = sc[t];
        int add = (t >= off) ? sc[t - off] : 0;
        __syncthreads();
        sc[t] = v + add;
        __syncthreads();
    }
    int excl = sc[t] - c0;
    rowptr[g * 512 + t] = base + excl;
    cnt[t] = excl;
    if (g == 0 && t == 0) rowptr[N_] = E_;
    __syncthreads();
    for (int i = t; i < 8192; i += 512) {
        int d = dstS[i];
        int p = atomicAdd(&cnt[d], 1);
        col[base + p] = g * 512 + (i >> 4);
    }
}

// =================== fused GIN layer (packed-add gather) ===================
// L0: gather from LDS (emb table + x). LAST: fused partitioner via MFMA epilogue.
constexpr int LDH = 264;
constexpr int COLCAP = 1024;
template<int L0, int LAST>
__global__ __launch_bounds__(512, LAST ? 4 : 8) void k_gin(
    const float* __restrict__ hIn, const int* __restrict__ rowptr,
    const int* __restrict__ col,
    const int* __restrict__ xIdx, const float* __restrict__ emb,
    const unsigned short* __restrict__ w1h, const unsigned short* __restrict__ w1l,
    const unsigned short* __restrict__ w2h, const unsigned short* __restrict__ w2l,
    const float* __restrict__ b1, const float* __restrict__ b2,
    const float* __restrict__ gamma, const float* __restrict__ beta,
    int relu_out, float* __restrict__ hOut,
    const unsigned short* __restrict__ pw1h, const unsigned short* __restrict__ pw1l,
    const float* __restrict__ pb1,
    const float* __restrict__ pW2, const float* __restrict__ pb2,
    float* __restrict__ pacc, float* __restrict__ pss, float* __restrict__ prs) {
    __shared__ int colS[COLCAP];
    __shared__ __attribute__((aligned(16))) unsigned short bufH[32 * LDH];
    __shared__ __attribute__((aligned(16))) unsigned short bufL[32 * LDH];
    __shared__ float embS[L0 ? 21 * 128 : 1];
    __shared__ int xS[L0 ? 512 : 1];
    __shared__ float ltS[LAST ? 32 * 5 : 1];
    int i = blockIdx.x;
    int xcd = i & 7;
    int slot = i >> 3;
    int g = (slot >> 4) * 8 + xcd;
    int tile = slot & 15;
    int rowBase = g * 512 + tile * 32;
    int t = threadIdx.x;
    int w = t >> 6, l = t & 63;
    int l15 = l & 15, quad = l >> 4;
    int half = l >> 5, lane4 = l & 31;

    int ebase = rowptr[rowBase];
    int ecnt  = rowptr[rowBase + 32] - ebase;
    bool inLds = (ecnt <= COLCAP);
    if (inLds)
        for (int j = t; j < ecnt; j += 512) colS[j] = col[ebase + j];
    if constexpr (L0) {
        for (int j = t; j < 21 * 128; j += 512) embS[j] = emb[j];
        if (t < 512) xS[t] = xIdx[(rowBase & ~511) + t];
    }
    __syncthreads();

    const f32x4_t* h4 = (const f32x4_t*)hIn;
    #pragma unroll
    for (int jj = 0; jj < 2; jj++) {
        int row = w * 4 + half * 2 + jj;
        int node = rowBase + row;
        int beg = rowptr[node], end = rowptr[node + 1];
        f32x4_t a;
        if constexpr (L0)
            a = *(const f32x4_t*)&embS[xS[node & 511] * 128 + lane4 * 4];
        else
            a = h4[node * 32 + lane4];
        int e = beg;
        for (; e + 8 <= end; e += 8) {
            int c[8];
            #pragma unroll
            for (int u = 0; u < 8; u++)
                c[u] = inLds ? colS[e - ebase + u] : col[e + u];
            f32x4_t p[8];
            #pragma unroll
            for (int u = 0; u < 8; u++) {
                if constexpr (L0)
                    p[u] = *(const f32x4_t*)&embS[xS[c[u] & 511] * 128 + lane4 * 4];
                else
                    p[u] = h4[c[u] * 32 + lane4];
            }
            // tree-reduce: short dependency chains, packed adds
            f32x4_t s01 = p[0] + p[1], s23 = p[2] + p[3];
            f32x4_t s45 = p[4] + p[5], s67 = p[6] + p[7];
            a += (s01 + s23) + (s45 + s67);
        }
        for (; e < end; e++) {
            int c = inLds ? colS[e - ebase] : col[e];
            f32x4_t p;
            if constexpr (L0)
                p = *(const f32x4_t*)&embS[xS[c & 511] * 128 + lane4 * 4];
            else
                p = h4[c * 32 + lane4];
            a += p;
        }
        unsigned short h0 = f2bf(a[0]), h1 = f2bf(a[1]), h2s = f2bf(a[2]), h3 = f2bf(a[3]);
        uint2 hv, lv;
        hv.x = (unsigned)h0 | ((unsigned)h1 << 16);
        hv.y = (unsigned)h2s | ((unsigned)h3 << 16);
        lv.x = (unsigned)f2bf(a[0] - bf2f(h0)) | ((unsigned)f2bf(a[1] - bf2f(h1)) << 16);
        lv.y = (unsigned)f2bf(a[2] - bf2f(h2s)) | ((unsigned)f2bf(a[3] - bf2f(h3)) << 16);
        *(uint2*)&bufH[row * LDH + lane4 * 4] = hv;
        *(uint2*)&bufL[row * LDH + lane4 * 4] = lv;
    }
    __syncthreads();

    // ---- MLP1 ----
    f32x4_t acc[2][2];
    #pragma unroll
    for (int nt = 0; nt < 2; nt++) {
        float bb = b1[w * 32 + nt * 16 + l15];
        acc[0][nt] = (f32x4_t){bb, bb, bb, bb};
        acc[1][nt] = (f32x4_t){bb, bb, bb, bb};
    }
    #pragma unroll
    for (int kk = 0; kk < 4; kk++) {
        bf16x8_t ah[2], al[2];
        #pragma unroll
        for (int mt = 0; mt < 2; mt++) {
            int addr = (mt * 16 + l15) * LDH + kk * 32 + quad * 8;
            ah[mt] = *(const bf16x8_t*)&bufH[addr];
            al[mt] = *(const bf16x8_t*)&bufL[addr];
        }
        #pragma unroll
        for (int nt = 0; nt < 2; nt++) {
            int n16 = w * 2 + nt;
            int ga = (((n16 * 4 + kk) * 64 + l) << 3);
            bf16x8_t bh = *(const bf16x8_t*)&w1h[ga];
            bf16x8_t bl = *(const bf16x8_t*)&w1l[ga];
            acc[0][nt] = mfma3(ah[0], al[0], bh, bl, acc[0][nt]);
            acc[1][nt] = mfma3(ah[1], al[1], bh, bl, acc[1][nt]);
        }
    }
    __syncthreads();
    #pragma unroll
    for (int mt = 0; mt < 2; mt++)
        #pragma unroll
        for (int nt = 0; nt < 2; nt++) {
            int colL = w * 32 + nt * 16 + l15;
            #pragma unroll
            for (int r = 0; r < 4; r++) {
                int row = mt * 16 + quad * 4 + r;
                float v = fmaxf(acc[mt][nt][r], 0.f);
                unsigned short h0 = f2bf(v);
                bufH[row * LDH + colL] = h0;
                bufL[row * LDH + colL] = f2bf(v - bf2f(h0));
            }
        }
    __syncthreads();

    // ---- MLP2 ----
    f32x4_t acc2[2];
    {
        float bb = b2[w * 16 + l15];
        acc2[0] = (f32x4_t){bb, bb, bb, bb};
        acc2[1] = (f32x4_t){bb, bb, bb, bb};
    }
    #pragma unroll
    for (int kkG = 0; kkG < 8; kkG++) {
        bf16x8_t ah[2], al[2];
        #pragma unroll
        for (int mt = 0; mt < 2; mt++) {
            int addr = (mt * 16 + l15) * LDH + kkG * 32 + quad * 8;
            ah[mt] = *(const bf16x8_t*)&bufH[addr];
            al[mt] = *(const bf16x8_t*)&bufL[addr];
        }
        int ga = (((w * 8 + kkG) * 64 + l) << 3);
        bf16x8_t bh = *(const bf16x8_t*)&w2h[ga];
        bf16x8_t bl = *(const bf16x8_t*)&w2l[ga];
        acc2[0] = mfma3(ah[0], al[0], bh, bl, acc2[0]);
        acc2[1] = mfma3(ah[1], al[1], bh, bl, acc2[1]);
    }
    // ---- BN (+ReLU) ----
    int colC = w * 16 + l15;
    float gm = BN_SCALE_ * gamma[colC];
    float be = beta[colC];
    if constexpr (!LAST) {
        #pragma unroll
        for (int mt = 0; mt < 2; mt++)
            #pragma unroll
            for (int r = 0; r < 4; r++) {
                int row = mt * 16 + quad * 4 + r;
                float v = fmaf(acc2[mt][r], gm, be);
                if (relu_out) v = fmaxf(v, 0.f);
                hOut[(size_t)(rowBase + row) * 128 + colC] = v;
            }
    } else {
        // ============ fused partitioner (MFMA MLP1) + cf1 partials per 32-node chunk ============
        __syncthreads();   // main-path bufH/bufL reads done; safe to overwrite
        // write z (post-BN, no relu) as bf16 hi/lo into bufH/bufL (cols 0..127)
        #pragma unroll
        for (int mt = 0; mt < 2; mt++)
            #pragma unroll
            for (int r = 0; r < 4; r++) {
                int row = mt * 16 + quad * 4 + r;
                float v = fmaf(acc2[mt][r], gm, be);
                unsigned short h0 = f2bf(v);
                bufH[row * LDH + colC] = h0;
                bufL[row * LDH + colC] = f2bf(v - bf2f(h0));
            }
        __syncthreads();
        // MLP1 via MFMA: ht = relu(z @ pW1pad + pb1); wave w -> tile (mt=w>>2, nt=w&3)
        {
            int mtw = w >> 2, ntw = w & 3;
            int ocol = ntw * 16 + l15;
            float bb = (ocol < NHID_) ? pb1[ocol] : 0.f;
            f32x4_t acch = (f32x4_t){bb, bb, bb, bb};
            #pragma unroll
            for (int kk = 0; kk < 4; kk++) {
                int addr = (mtw * 16 + l15) * LDH + kk * 32 + quad * 8;
                bf16x8_t ah = *(const bf16x8_t*)&bufH[addr];
                bf16x8_t al = *(const bf16x8_t*)&bufL[addr];
                int ga = (((ntw * 4 + kk) * 64 + l) << 3);
                bf16x8_t bh = *(const bf16x8_t*)&pw1h[ga];
                bf16x8_t bl = *(const bf16x8_t*)&pw1l[ga];
                acch = mfma3(ah, al, bh, bl, acch);
            }
            // store ht fp32 in free cols 128.. of bufH (float view: row*132 + 64 + col)
            float* htF = (float*)bufH;
            #pragma unroll
            for (int r = 0; r < 4; r++) {
                int row = mtw * 16 + quad * 4 + r;
                htF[row * 132 + 64 + ocol] = fmaxf(acch[r], 0.f);
            }
        }
        __syncthreads();
        // MLP2 logits: lt = ht @ pW2 + pb2, pW2 [50][5]
        {
            float* htF = (float*)bufH;
            if (t < 160) {
                int row = t / 5, kk5 = t % 5;
                float a = pb2[kk5];
                for (int c = 0; c < NHID_; c++)
                    a = fmaf(htF[row * 132 + 64 + c], pW2[c * K_ + kk5], a);
                ltS[row * 5 + kk5] = a;
            }
        }
        __syncthreads();
        // softmax per row
        if (t < 32) {
            float l0 = ltS[t*5], l1 = ltS[t*5+1], l2 = ltS[t*5+2],
                  l3 = ltS[t*5+3], l4 = ltS[t*5+4];
            float m = fmaxf(fmaxf(fmaxf(l0, l1), fmaxf(l2, l3)), l4);
            float e0 = expf(l0 - m), e1 = expf(l1 - m), e2 = expf(l2 - m),
                  e3 = expf(l3 - m), e4 = expf(l4 - m);
            float inv = 1.0f / (e0 + e1 + e2 + e3 + e4);
            ltS[t*5]   = e0*inv; ltS[t*5+1] = e1*inv; ltS[t*5+2] = e2*inv;
            ltS[t*5+3] = e3*inv; ltS[t*5+4] = e4*inv;
        }
        __syncthreads();
        // partials: pacc[c][k][d], prs[c][d], pss[c][k]; z reconstructed = hi+lo
        int cIdx = g * 16 + tile;
        for (int j = t; j < 640; j += 512) {
            int k = j >> 7, d = j & 127;
            float a = 0;
            #pragma unroll 8
            for (int r = 0; r < 32; r++) {
                float zv = bf2f(bufH[r * LDH + d]) + bf2f(bufL[r * LDH + d]);
                a = fmaf(ltS[r * 5 + k], zv, a);
            }
            pacc[((size_t)cIdx * 5 + k) * 128 + d] = a;
        }
        if (t < 128) {
            float a = 0;
            #pragma unroll 8
            for (int r = 0; r < 32; r++)
                a += bf2f(bufH[r * LDH + t]) + bf2f(bufL[r * LDH + t]);
            prs[cIdx * 128 + t] = a;
        } else if (t < 133) {
            int k = t - 128;
            float a = 0;
            #pragma unroll 8
            for (int r = 0; r < 32; r++) a += ltS[r * 5 + k];
            pss[cIdx * 5 + k] = a;
        }
    }
}

// =================== fused tail (multi-accumulator ILP in all K-loops) ===================
__global__ __launch_bounds__(1024) void k_tail(
    const float* __restrict__ pacc, const float* __restrict__ pss,
    const float* __restrict__ prs, const float* __restrict__ cbk,
    const float* __restrict__ Wq, const float* __restrict__ Wk,
    const float* __restrict__ Wv, const float* __restrict__ Wo,
    const float* __restrict__ gW1, const float* __restrict__ gb1,
    const float* __restrict__ gW2, const float* __restrict__ gb2,
    const float* __restrict__ cW1, const float* __restrict__ cb1,
    const float* __restrict__ cW2, const float* __restrict__ cb2,
    const float* __restrict__ cW3, const float* __restrict__ cb3,
    float* __restrict__ out) {
    __shared__ float cfS[5 * 128];
    __shared__ float zqS[5 * 128];
    __shared__ float catS[256];
    __shared__ float qS[128];
    __shared__ float kS[5 * 128];
    __shared__ float vS[5 * 128];
    __shared__ float awS[20];
    __shared__ float att1S[128];
    __shared__ float attP[4][128];
    __shared__ float g1P[8][64];
    __shared__ float g1S[64];
    __shared__ float g2P[4][128];
    __shared__ float fusedS[128];
    __shared__ float z1P[2][512];
    __shared__ float z1S[512];
    __shared__ float z2P[4][256];
    __shared__ float bd5[5][512];
    __shared__ int   bi5[5][512];
    __shared__ int   idxS[5];
    __shared__ float red[8];

    int g = blockIdx.x, t = threadIdx.x;

    // ---- Phase 1: reduce cf partials + residue (16 chunks of 32 nodes) ----
    if (t < 768) {
        int c = t >> 7, d = t & 127;
        if (c == 5) {
            float rs = 0;
            #pragma unroll
            for (int ch = 0; ch < 16; ch++) rs += prs[(g * 16 + ch) * 128 + d];
            catS[d] = rs * (1.0f / 512.0f);
        } else {
            float acc = 0, ss = 0;
            #pragma unroll
            for (int ch = 0; ch < 16; ch++) {
                int blk = g * 16 + ch;
                acc += pacc[((size_t)blk * 5 + c) * 128 + d];
                ss  += pss[blk * 5 + c];
            }
            cfS[c * 128 + d] = acc / (ss + EPS_);
        }
    }
    __syncthreads();

    // ---- Phase 2: VQ argmin ----
    if (t < 512) {
        const float4* cj = (const float4*)(cbk + (size_t)t * 128);
        float d2[5] = {0, 0, 0, 0, 0};
        #pragma unroll 8
        for (int q4 = 0; q4 < 32; q4++) {
            float4 c4 = cj[q4];
            #pragma unroll
            for (int k = 0; k < 5; k++) {
                float4 f4 = ((const float4*)(cfS + k * 128))[q4];
                float dx = f4.x - c4.x, dy = f4.y - c4.y;
                float dz = f4.z - c4.z, dw = f4.w - c4.w;
                d2[k] = fmaf(dx, dx, d2[k]); d2[k] = fmaf(dy, dy, d2[k]);
                d2[k] = fmaf(dz, dz, d2[k]); d2[k] = fmaf(dw, dw, d2[k]);
            }
        }
        #pragma unroll
        for (int k = 0; k < 5; k++) { bd5[k][t] = d2[k]; bi5[k][t] = t; }
    }
    __syncthreads();
    for (int s = 256; s > 0; s >>= 1) {
        if (t < s) {
            #pragma unroll
            for (int k = 0; k < 5; k++) {
                float bo = bd5[k][t + s]; int io = bi5[k][t + s];
                if (bo < bd5[k][t] || (bo == bd5[k][t] && io < bi5[k][t])) {
                    bd5[k][t] = bo; bi5[k][t] = io;
                }
            }
        }
        __syncthreads();
    }
    if (t < 5) idxS[t] = bi5[t][0];
    __syncthreads();
    if (t < 640) zqS[t] = cbk[(size_t)idxS[t >> 7] * 128 + (t & 127)];
    __syncthreads();

    // ---- Phase 3: q/k/v projections (4 independent accumulator chains) ----
    for (int o = t; o < 1408; o += 1024) {
        const float* Arow; const float* W; int dcol;
        if (o < 128)      { Arow = catS;                     W = Wq; dcol = o; }
        else if (o < 768) { Arow = &zqS[((o - 128) >> 7) * 128]; W = Wk; dcol = (o - 128) & 127; }
        else              { Arow = &zqS[((o - 768) >> 7) * 128]; W = Wv; dcol = (o - 768) & 127; }
        float a0 = 0, a1 = 0, a2 = 0, a3 = 0;
        for (int kk = 0; kk < 128; kk += 4) {
            a0 = fmaf(Arow[kk],     W[kk * 128 + dcol],       a0);
            a1 = fmaf(Arow[kk + 1], W[(kk + 1) * 128 + dcol], a1);
            a2 = fmaf(Arow[kk + 2], W[(kk + 2) * 128 + dcol], a2);
            a3 = fmaf(Arow[kk + 3], W[(kk + 3) * 128 + dcol], a3);
        }
        float acc = (a0 + a1) + (a2 + a3);
        if (o < 128)      qS[o] = acc;
        else if (o < 768) kS[o - 128] = acc;
        else              vS[o - 768] = acc;
    }
    __syncthreads();

    // ---- Phase 4: attention ----
    if (t < 20) {
        int hh = t / 5, j = t % 5;
        float s = 0;
        #pragma unroll
        for (int d2 = 0; d2 < 32; d2++)
            s = fmaf(qS[hh * 32 + d2], kS[j * 128 + hh * 32 + d2], s);
        awS[t] = s * 0.17677669529663687f;
    }
    __syncthreads();
    if (t < 4) {
        float m = -1e30f;
        for (int j = 0; j < 5; j++) m = fmaxf(m, awS[t * 5 + j]);
        float e[5], sum = 0;
        for (int j = 0; j < 5; j++) { e[j] = expf(awS[t * 5 + j] - m); sum += e[j]; }
        for (int j = 0; j < 5; j++) awS[t * 5 + j] = e[j] / sum;
    }
    __syncthreads();
    if (t < 128) {
        int hh = t >> 5;
        float a = 0;
        #pragma unroll
        for (int j = 0; j < 5; j++) a = fmaf(awS[hh * 5 + j], vS[j * 128 + t], a);
        att1S[t] = a;
    }
    __syncthreads();
    // Wo: split-K 4x32, 2 accumulator chains each
    if (t < 512) {
        int o = t & 127, kq = t >> 7;
        float a0 = 0, a1 = 0;
        #pragma unroll 8
        for (int i = 0; i < 32; i += 2) {
            int kk = kq * 32 + i;
            a0 = fmaf(att1S[kk],     Wo[kk * 128 + o],       a0);
            a1 = fmaf(att1S[kk + 1], Wo[(kk + 1) * 128 + o], a1);
        }
        attP[kq][o] = a0 + a1;
    }
    __syncthreads();
    if (t < 128) catS[128 + t] = attP[0][t] + attP[1][t] + attP[2][t] + attP[3][t];
    __syncthreads();

    // ---- Phase 5: gate ----
    if (t < 512) {
        int o = t & 63, kq = t >> 6;
        float a0 = 0, a1 = 0;
        #pragma unroll 8
        for (int i = 0; i < 32; i += 2) {
            int kk = kq * 32 + i;
            a0 = fmaf(catS[kk],     gW1[kk * 64 + o],       a0);
            a1 = fmaf(catS[kk + 1], gW1[(kk + 1) * 64 + o], a1);
        }
        g1P[kq][o] = a0 + a1;
    }
    __syncthreads();
    if (t < 64) {
        float a = gb1[t];
        #pragma unroll
        for (int q = 0; q < 8; q++) a += g1P[q][t];
        g1S[t] = fmaxf(a, 0.f);
    }
    __syncthreads();
    if (t < 512) {
        int o = t & 127, kq = t >> 7;
        float a0 = 0, a1 = 0;
        #pragma unroll 8
        for (int i = 0; i < 16; i += 2) {
            int kk = kq * 16 + i;
            a0 = fmaf(g1S[kk],     gW2[kk * 128 + o],       a0);
            a1 = fmaf(g1S[kk + 1], gW2[(kk + 1) * 128 + o], a1);
        }
        g2P[kq][o] = a0 + a1;
    }
    __syncthreads();
    if (t < 128) {
        float a = gb2[t] + g2P[0][t] + g2P[1][t] + g2P[2][t] + g2P[3][t];
        float gv = 1.f / (1.f + expf(-a));
        fusedS[t] = gv * catS[t] + (1.f - gv) * catS[128 + t];
    }
    __syncthreads();

    // ---- Phase 6: classifier ----
    // cls1: split-K 2x64, 4 accumulator chains
    {
        int o = t & 511, kq = t >> 9;
        float a0 = 0, a1 = 0, a2 = 0, a3 = 0;
        #pragma unroll 4
        for (int i = 0; i < 64; i += 4) {
            int kk = kq * 64 + i;
            a0 = fmaf(fusedS[kk],     cW1[kk * 512 + o],       a0);
            a1 = fmaf(fusedS[kk + 1], cW1[(kk + 1) * 512 + o], a1);
            a2 = fmaf(fusedS[kk + 2], cW1[(kk + 2) * 512 + o], a2);
            a3 = fmaf(fusedS[kk + 3], cW1[(kk + 3) * 512 + o], a3);
        }
        z1P[kq][o] = (a0 + a1) + (a2 + a3);
    }
    __syncthreads();
    if (t < 512) z1S[t] = fmaxf(z1P[0][t] + z1P[1][t] + cb1[t], 0.f);
    __syncthreads();
    // cls2: split-K 4x128, 4 accumulator chains
    {
        int o = t & 255, kq = t >> 8;
        float a0 = 0, a1 = 0, a2 = 0, a3 = 0;
        #pragma unroll 4
        for (int i = 0; i < 128; i += 4) {
            int kk = kq * 128 + i;
            a0 = fmaf(z1S[kk],     cW2[kk * 256 + o],       a0);
            a1 = fmaf(z1S[kk + 1], cW2[(kk + 1) * 256 + o], a1);
            a2 = fmaf(z1S[kk + 2], cW2[(kk + 2) * 256 + o], a2);
            a3 = fmaf(z1S[kk + 3], cW2[(kk + 3) * 256 + o], a3);
        }
        z2P[kq][o] = (a0 + a1) + (a2 + a3);
    }
    __syncthreads();
    if (t < 256) {
        float zv = fmaxf(z2P[0][t] + z2P[1][t] + z2P[2][t] + z2P[3][t] + cb2[t], 0.f);
        float p0 = zv * cW3[t * 2];
        float p1 = zv * cW3[t * 2 + 1];
        #pragma unroll
        for (int off = 32; off > 0; off >>= 1) {
            p0 += __shfl_down(p0, off, 64);
            p1 += __shfl_down(p1, off, 64);
        }
        int wv = t >> 6;
        if ((t & 63) == 0) { red[wv * 2] = p0; red[wv * 2 + 1] = p1; }
    }
    __syncthreads();
    if (t < 2)
        out[g * 2 + t] = cb3[t] + red[t] + red[2 + t] + red[4 + t] + red[6 + t];
}

// =================== launch ===================
extern "C" void kernel_launch(void* const* d_in, const int* in_sizes, int n_in,
                              void* d_out, int out_size, void* d_ws, size_t ws_size,
                              hipStream_t stream) {
    const int*   x          = (const int*)d_in[0];
    const int*   edge_index = (const int*)d_in[1];
    const float* emb      = (const float*)d_in[3];
    const float* gin_W1   = (const float*)d_in[4];
    const float* gin_b1   = (const float*)d_in[5];
    const float* gin_W2   = (const float*)d_in[6];
    const float* gin_b2   = (const float*)d_in[7];
    const float* bn_gamma = (const float*)d_in[8];
    const float* bn_beta  = (const float*)d_in[9];
    const float* part_W1  = (const float*)d_in[10];
    const float* part_b1  = (const float*)d_in[11];
    const float* part_W2  = (const float*)d_in[12];
    const float* part_b2  = (const float*)d_in[13];
    const float* Wq       = (const float*)d_in[14];
    const float* Wk       = (const float*)d_in[15];
    const float* Wv       = (const float*)d_in[16];
    const float* Wo       = (const float*)d_in[17];
    const float* gate_W1  = (const float*)d_in[18];
    const float* gate_b1  = (const float*)d_in[19];
    const float* gate_W2  = (const float*)d_in[20];
    const float* gate_b2  = (const float*)d_in[21];
    const float* codebook = (const float*)d_in[22];
    const float* cls_W1   = (const float*)d_in[23];
    const float* cls_b1   = (const float*)d_in[24];
    const float* cls_W2   = (const float*)d_in[25];
    const float* cls_b2   = (const float*)d_in[26];
    const float* cls_W3   = (const float*)d_in[27];
    const float* cls_b3   = (const float*)d_in[28];

    const int* dstp = edge_index + E_;

    // ---- workspace carve ----
    char* w = (char*)d_ws;
    float* hA = (float*)w;  w += (size_t)N_ * D_ * 4;   // L1 out
    float* hB = (float*)w;  w += (size_t)N_ * D_ * 4;   // L0 out
    int* rowptr = (int*)w;  w += (size_t)(N_ + 4) * 4;
    int* col    = (int*)w;  w += (size_t)E_ * 4;
    unsigned short* w1h = (unsigned short*)w;  w += (size_t)3 * 32768 * 2;
    unsigned short* w1l = (unsigned short*)w;  w += (size_t)3 * 32768 * 2;
    unsigned short* w2h = (unsigned short*)w;  w += (size_t)3 * 32768 * 2;
    unsigned short* w2l = (unsigned short*)w;  w += (size_t)3 * 32768 * 2;
    unsigned short* pw1h = (unsigned short*)w;  w += (size_t)8192 * 2;
    unsigned short* pw1l = (unsigned short*)w;  w += (size_t)8192 * 2;
    float* pacc = (float*)w;  w += (size_t)1024 * 5 * 128 * 4;
    float* pss  = (float*)w;  w += (size_t)1024 * 5 * 4;
    float* prs  = (float*)w;  w += (size_t)1024 * 128 * 4;

    // ---- prep + CSR (64 csr + 384 gin-weight + 16 part-W1 blocks) ----
    k_prepcsr<<<464, 512, 0, stream>>>(dstp, rowptr, col,
                                       gin_W1, gin_W2, w1h, w1l, w2h, w2l,
                                       part_W1, pw1h, pw1l);

    // ---- GIN: L0 (emb LDS) -> hB; L1 hB -> hA; L2 hA -> fused partcf partials ----
    k_gin<1, 0><<<1024, 512, 0, stream>>>(
        hA, rowptr, col, x, emb,
        w1h, w1l, w2h, w2l,
        gin_b1, gin_b2, bn_gamma, bn_beta, 1, hB,
        nullptr, nullptr, nullptr, nullptr, nullptr, nullptr, nullptr, nullptr);
    k_gin<0, 0><<<1024, 512, 0, stream>>>(
        hB, rowptr, col, x, emb,
        w1h + 32768, w1l + 32768, w2h + 32768, w2l + 32768,
        gin_b1 + 256, gin_b2 + 128, bn_gamma + 128, bn_beta + 128, 1, hA,
        nullptr, nullptr, nullptr, nullptr, nullptr, nullptr, nullptr, nullptr);
    k_gin<0, 1><<<1024, 512, 0, stream>>>(
        hA, rowptr, col, x, emb,
        w1h + 65536, w1l + 65536, w2h + 65536, w2l + 65536,
        gin_b1 + 512, gin_b2 + 256, bn_gamma + 256, bn_beta + 256, 0, nullptr,
        pw1h, pw1l, part_b1, part_W2, part_b2, pacc, pss, prs);

    // ---- tail ----
    k_tail<<<B_, 1024, 0, stream>>>(pacc, pss, prs, codebook,
                                    Wq, Wk, Wv, Wo,
                                    gate_W1, gate_b1, gate_W2, gate_b2,
                                    cls_W1, cls_b1, cls_W2, cls_b2, cls_W3, cls_b3,
                                    (float*)d_out);
}